// Round 20
// baseline (682.576 us; speedup 1.0000x reference)
//
#include <hip/hip_runtime.h>
#include <hip/hip_bf16.h>

// ---------------------------------------------------------------------------
// Phase 1a: CSR build by dst
// ---------------------------------------------------------------------------

__global__ __launch_bounds__(256) void sge_count(
    const int* __restrict__ dst, int* __restrict__ cnt, int nE) {
  int e = blockIdx.x * 256 + threadIdx.x;
  if (e >= nE) return;
  atomicAdd(&cnt[dst[e]], 1);
}

__global__ __launch_bounds__(256) void sge_blocksum(
    const int* __restrict__ cnt, int* __restrict__ bsum, int N) {
  int i = blockIdx.x * 256 + threadIdx.x;
  int v = (i < N) ? cnt[i] : 0;
#pragma unroll
  for (int o = 1; o < 64; o <<= 1) v += __shfl_xor(v, o);
  __shared__ int ws[4];
  int lane = threadIdx.x & 63, wid = threadIdx.x >> 6;
  if (lane == 0) ws[wid] = v;
  __syncthreads();
  if (threadIdx.x == 0)
    bsum[blockIdx.x] = ws[0] + ws[1] + ws[2] + ws[3];
}

__global__ __launch_bounds__(64) void sge_scan_top(
    int* __restrict__ bsum, int* __restrict__ offs, int nb, int N, int nE) {
  int lane = threadIdx.x;
  int carry = 0;
  for (int base = 0; base < nb; base += 64) {
    int i = base + lane;
    int v = (i < nb) ? bsum[i] : 0;
    int s = v;
#pragma unroll
    for (int o = 1; o < 64; o <<= 1) {
      int t = __shfl_up(s, o);
      if (lane >= o) s += t;
    }
    if (i < nb) bsum[i] = carry + s - v;  // exclusive
    carry += __shfl(s, 63);
  }
  if (lane == 0) offs[N] = nE;
}

__global__ __launch_bounds__(256) void sge_scan_block(
    const int* __restrict__ cnt, const int* __restrict__ bsum,
    int* __restrict__ offs, int* __restrict__ pos, int N) {
  int i = blockIdx.x * 256 + threadIdx.x;
  int v = (i < N) ? cnt[i] : 0;
  int lane = threadIdx.x & 63, wid = threadIdx.x >> 6;
  int s = v;
#pragma unroll
  for (int o = 1; o < 64; o <<= 1) {
    int t = __shfl_up(s, o);
    if (lane >= o) s += t;
  }
  __shared__ int ws[4];
  if (lane == 63) ws[wid] = s;
  __syncthreads();
  int wbase = 0;
  for (int w = 0; w < wid; ++w) wbase += ws[w];
  if (i < N) {
    int o = bsum[blockIdx.x] + wbase + s - v;
    offs[i] = o;
    pos[i] = o;
  }
}

__global__ __launch_bounds__(256) void sge_fill(
    const int* __restrict__ src, const int* __restrict__ dst,
    int* __restrict__ pos, int* __restrict__ sorted_src, int nE) {
  int e = blockIdx.x * 256 + threadIdx.x;
  if (e >= nE) return;
  int p = atomicAdd(&pos[dst[e]], 1);
  sorted_src[p] = src[e];
}

// ---------------------------------------------------------------------------
// Phase 1b (fused): gather-aggregate INTO the LDS tile, then z = xs @ W.
// CSR arrays live AFTER the z region (no overlay with z writes).
// ---------------------------------------------------------------------------
__global__ __launch_bounds__(256) void sge_gemm(
    const float* __restrict__ x, const int* __restrict__ sorted_src,
    const int* __restrict__ offs, const float* __restrict__ W,
    float* __restrict__ z) {
  __shared__ float xs[32][128];
  int n0 = blockIdx.x * 32;
  int t = threadIdx.x;

  {
    int r = t >> 3;          // node slot 0..31
    int c0 = (t & 7) << 4;   // 16-column span
    int node = n0 + r;       // N % 32 == 0: always valid
    int e0 = offs[node], e1 = offs[node + 1];
    float4 a0 = {0.f, 0.f, 0.f, 0.f}, a1 = {0.f, 0.f, 0.f, 0.f};
    float4 a2 = {0.f, 0.f, 0.f, 0.f}, a3 = {0.f, 0.f, 0.f, 0.f};
    for (int e = e0; e < e1; ++e) {
      int s = sorted_src[e];  // uniform across the 8 threads of this node
      const float4* xr = (const float4*)&x[(size_t)s * 128 + c0];
      float4 v0 = xr[0], v1 = xr[1], v2 = xr[2], v3 = xr[3];
      a0.x += v0.x; a0.y += v0.y; a0.z += v0.z; a0.w += v0.w;
      a1.x += v1.x; a1.y += v1.y; a1.z += v1.z; a1.w += v1.w;
      a2.x += v2.x; a2.y += v2.y; a2.z += v2.z; a2.w += v2.w;
      a3.x += v3.x; a3.y += v3.y; a3.z += v3.z; a3.w += v3.w;
    }
    float inv = 1.0f / fmaxf((float)(e1 - e0), 1.0f);
    float4* xw = (float4*)&xs[r][c0];
    float4 w0, w1, w2, w3;
    w0.x = a0.x * inv; w0.y = a0.y * inv; w0.z = a0.z * inv; w0.w = a0.w * inv;
    w1.x = a1.x * inv; w1.y = a1.y * inv; w1.z = a1.z * inv; w1.w = a1.w * inv;
    w2.x = a2.x * inv; w2.y = a2.y * inv; w2.z = a2.z * inv; w2.w = a2.w * inv;
    w3.x = a3.x * inv; w3.y = a3.y * inv; w3.z = a3.z * inv; w3.w = a3.w * inv;
    xw[0] = w0; xw[1] = w1; xw[2] = w2; xw[3] = w3;
  }
  __syncthreads();

  int wv = t >> 6, lane = t & 63;
  int r0 = wv * 8;
  float acc[8][4];
#pragma unroll
  for (int r = 0; r < 8; ++r)
#pragma unroll
    for (int q = 0; q < 4; ++q) acc[r][q] = 0.f;
  for (int k = 0; k < 128; k += 4) {
    float4 xv[8];
#pragma unroll
    for (int r = 0; r < 8; ++r) xv[r] = *(const float4*)&xs[r0 + r][k];
#pragma unroll
    for (int kk = 0; kk < 4; ++kk) {
      const float* Wr = W + (k + kk) * 256 + lane;
      float w0 = Wr[0], w1 = Wr[64], w2 = Wr[128], w3 = Wr[192];
#pragma unroll
      for (int r = 0; r < 8; ++r) {
        float xk = (kk == 0) ? xv[r].x
                 : (kk == 1) ? xv[r].y
                 : (kk == 2) ? xv[r].z : xv[r].w;
        acc[r][0] = fmaf(xk, w0, acc[r][0]);
        acc[r][1] = fmaf(xk, w1, acc[r][1]);
        acc[r][2] = fmaf(xk, w2, acc[r][2]);
        acc[r][3] = fmaf(xk, w3, acc[r][3]);
      }
    }
  }
#pragma unroll
  for (int r = 0; r < 8; ++r) {
    float* zr = z + (long long)(n0 + r0 + r) * 256 + lane;
#pragma unroll
    for (int q = 0; q < 4; ++q) zr[q * 64] = acc[r][q];
  }
}

// ---------------------------------------------------------------------------
// Phase 2 (v21): v14 minus the C[32] array. Final-eps refresh uses
// V = exp2(1.5625 * log2(V))  (eps 0.078125 -> 0.05; v11-validated).
// Live set drops ~32 regs -> more waves/SIMD under the unified VGPR file.
// ---------------------------------------------------------------------------
template <int CTRL>
__device__ __forceinline__ float dpp_max(float x) {
  int r = __builtin_amdgcn_update_dpp(__float_as_int(x), __float_as_int(x),
                                      CTRL, 0xF, 0xF, false);
  return fmaxf(x, __int_as_float(r));
}
template <int CTRL>
__device__ __forceinline__ float dpp_add(float x) {
  int r = __builtin_amdgcn_update_dpp(0, __float_as_int(x), CTRL, 0xF, 0xF, true);
  return x + __int_as_float(r);
}

__global__ __launch_bounds__(256, 4) void sge_energy(
    const float* __restrict__ z, const int* __restrict__ ep,
    const int* __restrict__ en, float* __restrict__ partial, int nP) {
  __shared__ __align__(16) float Ebuf[2][2][64];  // [pair][wave][64]
  __shared__ __align__(16) float Nbuf[2][2][64];  // [pair][wave][64] norms
  __shared__ float red[2][2];

  int t = threadIdx.x;
  int pl = t >> 7;        // pair-local index 0/1
  int tp = t & 127;       // thread within pair
  int w = tp >> 6;        // wave-in-pair: 0={xy,yx}, 1={xx,yy}
  int l = tp & 63;
  int row = l & 31;
  int own = l & 32;       // 0 = x-rows half, 32 = y-rows half

  int pair = blockIdx.x * 2 + pl;
  bool isPos = pair < nP;
  int idx = isPos ? pair : pair - nP;
  const int* E = isPos ? ep : en;
  int na = E[idx], nb = E[idx + nP];

  // own row straight from global
  const float* zrow = z + (size_t)(own ? nb : na) * 256 + row * 8;
  float4 r0 = ((const float4*)zrow)[0];
  float4 r1 = ((const float4*)zrow)[1];
  float xr[8];
  xr[0] = r0.x; xr[1] = r0.y; xr[2] = r0.z; xr[3] = r0.w;
  xr[4] = r1.x; xr[5] = r1.y; xr[6] = r1.z; xr[7] = r1.w;

  // own squared norm -> LDS exchange (same rb addressing as Ebuf)
  float nself = xr[0] * xr[0];
  nself = fmaf(xr[1], xr[1], nself); nself = fmaf(xr[2], xr[2], nself);
  nself = fmaf(xr[3], xr[3], nself); nself = fmaf(xr[4], xr[4], nself);
  nself = fmaf(xr[5], xr[5], nself); nself = fmaf(xr[6], xr[6], nself);
  nself = fmaf(xr[7], xr[7], nself);
  Nbuf[pl][w][l] = nself;
  __builtin_amdgcn_wave_barrier();

  bool colIsX = (w == 0) ? (own != 0) : (own == 0);
  const float4* zc = (const float4*)(z + (size_t)(colIsX ? na : nb) * 256);
  int rb = (w == 0) ? (own ^ 32) : own;
  const float* Nw = Nbuf[pl][w] + rb;

  const float RLNE = 1.44269504088896340736f;  // log2(e)
  const float LN2 = 0.69314718055994530942f;
  const float LN32 = 3.46573590279972654709f;  // ln(32)
  const float K20 = RLNE / 10.0f;

  // build V = 2^(-C*k2_0); norm-form distance; C NOT stored
  float V[32];
#pragma unroll
  for (int jq = 0; jq < 8; ++jq) {
    float4 nj4 = ((const float4*)Nw)[jq];
    float4 a[8];
#pragma unroll
    for (int k = 0; k < 4; ++k) {
      a[2 * k] = zc[8 * jq + 2 * k];
      a[2 * k + 1] = zc[8 * jq + 2 * k + 1];
    }
#pragma unroll
    for (int k = 0; k < 4; ++k) {
      int j = jq * 4 + k;
      float4 a0 = a[2 * k], a1 = a[2 * k + 1];
      float d = xr[0] * a0.x;
      d = fmaf(xr[1], a0.y, d); d = fmaf(xr[2], a0.z, d);
      d = fmaf(xr[3], a0.w, d); d = fmaf(xr[4], a1.x, d);
      d = fmaf(xr[5], a1.y, d); d = fmaf(xr[6], a1.z, d);
      d = fmaf(xr[7], a1.w, d);
      float nj = (k == 0) ? nj4.x : (k == 1) ? nj4.y : (k == 2) ? nj4.z : nj4.w;
      float sq = fmaf(-2.0f, d, nself + nj);
      float Cv = __builtin_amdgcn_sqrtf(fmaxf(sq, 0.0f) + 1e-8f);
      V[j] = __builtin_amdgcn_exp2f(-Cv * K20);
    }
  }

  float* Ew = Ebuf[pl][w];

  float P = 0.0f;
  float epsv = 10.0f;

#pragma unroll 1
  for (int it = 0; it < 9; ++it) {
    float eps = (it == 8) ? 0.05f : epsv;
    float k2 = RLNE / eps;
    float eln2 = eps * LN2;
    float c32 = eps * LN32;

    if (it == 8) {
      // eps 0.078125 -> 0.05: exponent scales by exactly 1.5625
#pragma unroll
      for (int j = 0; j < 32; ++j)
        V[j] = __builtin_amdgcn_exp2f(1.5625f * __builtin_amdgcn_logf(V[j]));
    } else if (it > 0) {
#pragma unroll
      for (int j = 0; j < 32; ++j) V[j] *= V[j];
    }

    float mOwn, mRead;
    if (it >= 7) {
      float m = P;
      m = dpp_max<0x111>(m);
      m = dpp_max<0x112>(m);
      m = dpp_max<0x114>(m);
      m = dpp_max<0x118>(m);
      m = dpp_max<0x142>(m);  // lanes 31/63 hold half maxes
      float g0 = __int_as_float(__builtin_amdgcn_readlane(__float_as_int(m), 31));
      float g1 = __int_as_float(__builtin_amdgcn_readlane(__float_as_int(m), 63));
      mOwn = own ? g1 : g0;
      mRead = (w == 0) ? (own ? g0 : g1) : mOwn;
    } else {
      mOwn = 0.0f;
      mRead = 0.0f;
    }

    Ew[l] = __builtin_amdgcn_exp2f((P - mOwn) * k2);
    __builtin_amdgcn_wave_barrier();

    float s0 = 0.f, s1 = 0.f, s2 = 0.f, s3 = 0.f;
#pragma unroll
    for (int jq = 0; jq < 8; ++jq) {
      float4 Ev = ((const float4*)(Ew + rb))[jq];
      s0 = fmaf(Ev.x, V[4 * jq + 0], s0);
      s1 = fmaf(Ev.y, V[4 * jq + 1], s1);
      s2 = fmaf(Ev.z, V[4 * jq + 2], s2);
      s3 = fmaf(Ev.w, V[4 * jq + 3], s3);
    }
    float s = fmaxf((s0 + s1) + (s2 + s3), 1e-37f);
    __builtin_amdgcn_wave_barrier();  // reads complete before next write

    P = 0.5f * (P + (c32 - mRead - eln2 * __builtin_amdgcn_logf(s)));
    epsv *= 0.5f;
  }

  // wave sums via DPP
  float d = P;
  d = dpp_add<0x111>(d);
  d = dpp_add<0x112>(d);
  d = dpp_add<0x114>(d);
  d = dpp_add<0x118>(d);
  d = dpp_add<0x142>(d);
  float s31 = __int_as_float(__builtin_amdgcn_readlane(__float_as_int(d), 31));
  float s63 = __int_as_float(__builtin_amdgcn_readlane(__float_as_int(d), 63));
  if (l == 0) red[pl][w] = s31 + s63;
  __syncthreads();
  if (t == 0) {
    float tot = 0.0f;
#pragma unroll
    for (int q = 0; q < 2; ++q) {
      int pr = blockIdx.x * 2 + q;
      float e = (red[q][0] - red[q][1]) * (1.0f / 32.0f);
      float term;
      if (pr < nP) {
        term = e * e;
      } else {
        float mm = fmaxf(1.0f - e, 0.0f);
        term = mm * mm;
      }
      tot += term;
    }
    partial[blockIdx.x] = tot;   // no atomics: per-block partial
  }
}

// single-block final reduction: out = sum(partial) / nP
__global__ __launch_bounds__(1024) void sge_reduce(
    const float* __restrict__ partial, int n, float invnP,
    float* __restrict__ out) {
  __shared__ float ws[16];
  float s = 0.0f;
  for (int i = threadIdx.x; i < n; i += 1024) s += partial[i];
#pragma unroll
  for (int o = 1; o < 64; o <<= 1) s += __shfl_xor(s, o);
  if ((threadIdx.x & 63) == 0) ws[threadIdx.x >> 6] = s;
  __syncthreads();
  if (threadIdx.x == 0) {
    float tt = 0.0f;
#pragma unroll
    for (int q = 0; q < 16; ++q) tt += ws[q];
    out[0] = tt * invnP;
  }
}

// ---------------------------------------------------------------------------
extern "C" void kernel_launch(void* const* d_in, const int* in_sizes, int n_in,
                              void* d_out, int out_size, void* d_ws, size_t ws_size,
                              hipStream_t stream) {
  const float* x  = (const float*)d_in[0];
  const int*   ei = (const int*)d_in[1];
  const int*   ep = (const int*)d_in[2];
  const int*   en = (const int*)d_in[3];
  const float* W  = (const float*)d_in[4];
  float* out = (float*)d_out;

  int N  = in_sizes[0] / 128;   // 100000 nodes
  int nE = in_sizes[1] / 2;     // 1600000 edges
  int nP = in_sizes[2] / 2;     // 30000 pos (== neg)

  size_t zBytes   = (size_t)N * 256 * sizeof(float);
  size_t aggBytes = (size_t)N * 128 * sizeof(float);
  if (ws_size < zBytes + aggBytes) return;

  char* ws = (char*)d_ws;
  float* z = (float*)ws;  // [0, zBytes): written by gemm, read by energy

  // CSR temporaries + partials AFTER the z region (no overlap with z)
  int* base2      = (int*)(ws + zBytes);
  int* cnt        = base2;                 // N
  int* offs       = cnt + N;               // N+1
  int* pos        = offs + N + 1;          // N
  int* bsum       = pos + N;               // <= 4096
  int* sorted_src = bsum + 4096;           // nE
  float* partial  = (float*)(sorted_src + nE);  // nP floats

  int nb = (N + 255) / 256;

  hipMemsetAsync(cnt, 0, (size_t)N * sizeof(int), stream);

  const int* src = ei;
  const int* dst = ei + nE;

  int eb = (nE + 255) / 256;
  sge_count<<<eb, 256, 0, stream>>>(dst, cnt, nE);
  sge_blocksum<<<nb, 256, 0, stream>>>(cnt, bsum, N);
  sge_scan_top<<<1, 64, 0, stream>>>(bsum, offs, nb, N, nE);
  sge_scan_block<<<nb, 256, 0, stream>>>(cnt, bsum, offs, pos, N);
  sge_fill<<<eb, 256, 0, stream>>>(src, dst, pos, sorted_src, nE);

  sge_gemm<<<(N + 31) / 32, 256, 0, stream>>>(x, sorted_src, offs, W, z);

  sge_energy<<<nP, 256, 0, stream>>>(z, ep, en, partial, nP);
  sge_reduce<<<1, 1024, 0, stream>>>(partial, nP, 1.0f / (float)nP, out);
}

// Round 21
// 660.872 us; speedup vs baseline: 1.0328x; 1.0328x over previous
//
#include <hip/hip_runtime.h>
#include <hip/hip_bf16.h>

// ---------------------------------------------------------------------------
// Phase 1a: CSR build by dst
// ---------------------------------------------------------------------------

__global__ __launch_bounds__(256) void sge_count(
    const int* __restrict__ dst, int* __restrict__ cnt, int nE) {
  int e = blockIdx.x * 256 + threadIdx.x;
  if (e >= nE) return;
  atomicAdd(&cnt[dst[e]], 1);
}

__global__ __launch_bounds__(256) void sge_blocksum(
    const int* __restrict__ cnt, int* __restrict__ bsum, int N) {
  int i = blockIdx.x * 256 + threadIdx.x;
  int v = (i < N) ? cnt[i] : 0;
#pragma unroll
  for (int o = 1; o < 64; o <<= 1) v += __shfl_xor(v, o);
  __shared__ int ws[4];
  int lane = threadIdx.x & 63, wid = threadIdx.x >> 6;
  if (lane == 0) ws[wid] = v;
  __syncthreads();
  if (threadIdx.x == 0)
    bsum[blockIdx.x] = ws[0] + ws[1] + ws[2] + ws[3];
}

__global__ __launch_bounds__(64) void sge_scan_top(
    int* __restrict__ bsum, int* __restrict__ offs, int nb, int N, int nE) {
  int lane = threadIdx.x;
  int carry = 0;
  for (int base = 0; base < nb; base += 64) {
    int i = base + lane;
    int v = (i < nb) ? bsum[i] : 0;
    int s = v;
#pragma unroll
    for (int o = 1; o < 64; o <<= 1) {
      int t = __shfl_up(s, o);
      if (lane >= o) s += t;
    }
    if (i < nb) bsum[i] = carry + s - v;  // exclusive
    carry += __shfl(s, 63);
  }
  if (lane == 0) offs[N] = nE;
}

__global__ __launch_bounds__(256) void sge_scan_block(
    const int* __restrict__ cnt, const int* __restrict__ bsum,
    int* __restrict__ offs, int* __restrict__ pos, int N) {
  int i = blockIdx.x * 256 + threadIdx.x;
  int v = (i < N) ? cnt[i] : 0;
  int lane = threadIdx.x & 63, wid = threadIdx.x >> 6;
  int s = v;
#pragma unroll
  for (int o = 1; o < 64; o <<= 1) {
    int t = __shfl_up(s, o);
    if (lane >= o) s += t;
  }
  __shared__ int ws[4];
  if (lane == 63) ws[wid] = s;
  __syncthreads();
  int wbase = 0;
  for (int w = 0; w < wid; ++w) wbase += ws[w];
  if (i < N) {
    int o = bsum[blockIdx.x] + wbase + s - v;
    offs[i] = o;
    pos[i] = o;
  }
}

__global__ __launch_bounds__(256) void sge_fill(
    const int* __restrict__ src, const int* __restrict__ dst,
    int* __restrict__ pos, int* __restrict__ sorted_src, int nE) {
  int e = blockIdx.x * 256 + threadIdx.x;
  if (e >= nE) return;
  int p = atomicAdd(&pos[dst[e]], 1);
  sorted_src[p] = src[e];
}

// ---------------------------------------------------------------------------
// Phase 1b (fused): gather-aggregate INTO the LDS tile, then z = xs @ W.
// Gather unrolled 2 edges/iter: 8 independent float4 loads in flight.
// CSR arrays live AFTER the z region (no overlay with z writes).
// ---------------------------------------------------------------------------
__global__ __launch_bounds__(256) void sge_gemm(
    const float* __restrict__ x, const int* __restrict__ sorted_src,
    const int* __restrict__ offs, const float* __restrict__ W,
    float* __restrict__ z) {
  __shared__ float xs[32][128];
  int n0 = blockIdx.x * 32;
  int t = threadIdx.x;

  {
    int r = t >> 3;          // node slot 0..31
    int c0 = (t & 7) << 4;   // 16-column span
    int node = n0 + r;       // N % 32 == 0: always valid
    int e0 = offs[node], e1 = offs[node + 1];
    float4 a0 = {0.f, 0.f, 0.f, 0.f}, a1 = {0.f, 0.f, 0.f, 0.f};
    float4 a2 = {0.f, 0.f, 0.f, 0.f}, a3 = {0.f, 0.f, 0.f, 0.f};
    float4 b0 = {0.f, 0.f, 0.f, 0.f}, b1 = {0.f, 0.f, 0.f, 0.f};
    float4 b2 = {0.f, 0.f, 0.f, 0.f}, b3 = {0.f, 0.f, 0.f, 0.f};
    int e = e0;
    for (; e + 2 <= e1; e += 2) {
      int s0 = sorted_src[e];
      int s1 = sorted_src[e + 1];
      const float4* xr0 = (const float4*)&x[(size_t)s0 * 128 + c0];
      const float4* xr1 = (const float4*)&x[(size_t)s1 * 128 + c0];
      float4 u0 = xr0[0], u1 = xr0[1], u2 = xr0[2], u3 = xr0[3];
      float4 v0 = xr1[0], v1 = xr1[1], v2 = xr1[2], v3 = xr1[3];
      a0.x += u0.x; a0.y += u0.y; a0.z += u0.z; a0.w += u0.w;
      b0.x += v0.x; b0.y += v0.y; b0.z += v0.z; b0.w += v0.w;
      a1.x += u1.x; a1.y += u1.y; a1.z += u1.z; a1.w += u1.w;
      b1.x += v1.x; b1.y += v1.y; b1.z += v1.z; b1.w += v1.w;
      a2.x += u2.x; a2.y += u2.y; a2.z += u2.z; a2.w += u2.w;
      b2.x += v2.x; b2.y += v2.y; b2.z += v2.z; b2.w += v2.w;
      a3.x += u3.x; a3.y += u3.y; a3.z += u3.z; a3.w += u3.w;
      b3.x += v3.x; b3.y += v3.y; b3.z += v3.z; b3.w += v3.w;
    }
    if (e < e1) {
      int s0 = sorted_src[e];
      const float4* xr0 = (const float4*)&x[(size_t)s0 * 128 + c0];
      float4 u0 = xr0[0], u1 = xr0[1], u2 = xr0[2], u3 = xr0[3];
      a0.x += u0.x; a0.y += u0.y; a0.z += u0.z; a0.w += u0.w;
      a1.x += u1.x; a1.y += u1.y; a1.z += u1.z; a1.w += u1.w;
      a2.x += u2.x; a2.y += u2.y; a2.z += u2.z; a2.w += u2.w;
      a3.x += u3.x; a3.y += u3.y; a3.z += u3.z; a3.w += u3.w;
    }
    float inv = 1.0f / fmaxf((float)(e1 - e0), 1.0f);
    float4* xw = (float4*)&xs[r][c0];
    float4 w0, w1, w2, w3;
    w0.x = (a0.x + b0.x) * inv; w0.y = (a0.y + b0.y) * inv;
    w0.z = (a0.z + b0.z) * inv; w0.w = (a0.w + b0.w) * inv;
    w1.x = (a1.x + b1.x) * inv; w1.y = (a1.y + b1.y) * inv;
    w1.z = (a1.z + b1.z) * inv; w1.w = (a1.w + b1.w) * inv;
    w2.x = (a2.x + b2.x) * inv; w2.y = (a2.y + b2.y) * inv;
    w2.z = (a2.z + b2.z) * inv; w2.w = (a2.w + b2.w) * inv;
    w3.x = (a3.x + b3.x) * inv; w3.y = (a3.y + b3.y) * inv;
    w3.z = (a3.z + b3.z) * inv; w3.w = (a3.w + b3.w) * inv;
    xw[0] = w0; xw[1] = w1; xw[2] = w2; xw[3] = w3;
  }
  __syncthreads();

  int wv = t >> 6, lane = t & 63;
  int r0 = wv * 8;
  float acc[8][4];
#pragma unroll
  for (int r = 0; r < 8; ++r)
#pragma unroll
    for (int q = 0; q < 4; ++q) acc[r][q] = 0.f;
  for (int k = 0; k < 128; k += 4) {
    float4 xv[8];
#pragma unroll
    for (int r = 0; r < 8; ++r) xv[r] = *(const float4*)&xs[r0 + r][k];
#pragma unroll
    for (int kk = 0; kk < 4; ++kk) {
      const float* Wr = W + (k + kk) * 256 + lane;
      float w0 = Wr[0], w1 = Wr[64], w2 = Wr[128], w3 = Wr[192];
#pragma unroll
      for (int r = 0; r < 8; ++r) {
        float xk = (kk == 0) ? xv[r].x
                 : (kk == 1) ? xv[r].y
                 : (kk == 2) ? xv[r].z : xv[r].w;
        acc[r][0] = fmaf(xk, w0, acc[r][0]);
        acc[r][1] = fmaf(xk, w1, acc[r][1]);
        acc[r][2] = fmaf(xk, w2, acc[r][2]);
        acc[r][3] = fmaf(xk, w3, acc[r][3]);
      }
    }
  }
#pragma unroll
  for (int r = 0; r < 8; ++r) {
    float* zr = z + (long long)(n0 + r0 + r) * 256 + lane;
#pragma unroll
    for (int q = 0; q < 4; ++q) zr[q * 64] = acc[r][q];
  }
}

// ---------------------------------------------------------------------------
// Phase 2 (v14, FROZEN — verified 3x): norm-form build via per-wave LDS norm
// exchange, global-direct column reads, C kept for the final-eps fresh-exp
// refresh, max-skip for iters 0..6, per-block partials (no atomics).
// Restructure attempts v10/v15/v17/v18/v21 all regressed or failed.
// ---------------------------------------------------------------------------
template <int CTRL>
__device__ __forceinline__ float dpp_max(float x) {
  int r = __builtin_amdgcn_update_dpp(__float_as_int(x), __float_as_int(x),
                                      CTRL, 0xF, 0xF, false);
  return fmaxf(x, __int_as_float(r));
}
template <int CTRL>
__device__ __forceinline__ float dpp_add(float x) {
  int r = __builtin_amdgcn_update_dpp(0, __float_as_int(x), CTRL, 0xF, 0xF, true);
  return x + __int_as_float(r);
}

__global__ __launch_bounds__(256, 4) void sge_energy(
    const float* __restrict__ z, const int* __restrict__ ep,
    const int* __restrict__ en, float* __restrict__ partial, int nP) {
  __shared__ __align__(16) float Ebuf[2][2][64];  // [pair][wave][64]
  __shared__ __align__(16) float Nbuf[2][2][64];  // [pair][wave][64] norms
  __shared__ float red[2][2];

  int t = threadIdx.x;
  int pl = t >> 7;        // pair-local index 0/1
  int tp = t & 127;       // thread within pair
  int w = tp >> 6;        // wave-in-pair: 0={xy,yx}, 1={xx,yy}
  int l = tp & 63;
  int row = l & 31;
  int own = l & 32;       // 0 = x-rows half, 32 = y-rows half

  int pair = blockIdx.x * 2 + pl;
  bool isPos = pair < nP;
  int idx = isPos ? pair : pair - nP;
  const int* E = isPos ? ep : en;
  int na = E[idx], nb = E[idx + nP];

  // own row straight from global
  const float* zrow = z + (size_t)(own ? nb : na) * 256 + row * 8;
  float4 r0 = ((const float4*)zrow)[0];
  float4 r1 = ((const float4*)zrow)[1];
  float xr[8];
  xr[0] = r0.x; xr[1] = r0.y; xr[2] = r0.z; xr[3] = r0.w;
  xr[4] = r1.x; xr[5] = r1.y; xr[6] = r1.z; xr[7] = r1.w;

  // own squared norm -> LDS exchange (same rb addressing as Ebuf)
  float nself = xr[0] * xr[0];
  nself = fmaf(xr[1], xr[1], nself); nself = fmaf(xr[2], xr[2], nself);
  nself = fmaf(xr[3], xr[3], nself); nself = fmaf(xr[4], xr[4], nself);
  nself = fmaf(xr[5], xr[5], nself); nself = fmaf(xr[6], xr[6], nself);
  nself = fmaf(xr[7], xr[7], nself);
  Nbuf[pl][w][l] = nself;
  __builtin_amdgcn_wave_barrier();

  bool colIsX = (w == 0) ? (own != 0) : (own == 0);
  const float4* zc = (const float4*)(z + (size_t)(colIsX ? na : nb) * 256);
  int rb = (w == 0) ? (own ^ 32) : own;
  const float* Nw = Nbuf[pl][w] + rb;

  const float RLNE = 1.44269504088896340736f;  // log2(e)
  const float LN2 = 0.69314718055994530942f;
  const float LN32 = 3.46573590279972654709f;  // ln(32)
  const float K20 = RLNE / 10.0f;
  const float NK28 = -RLNE / 0.05f;            // -k2 at final eps

  // build C (kept) and V = 2^(-C*k2_0); norm-form distance
  float C[32], V[32];
#pragma unroll
  for (int jq = 0; jq < 8; ++jq) {
    float4 nj4 = ((const float4*)Nw)[jq];
    float4 a[8];
#pragma unroll
    for (int k = 0; k < 4; ++k) {
      a[2 * k] = zc[8 * jq + 2 * k];
      a[2 * k + 1] = zc[8 * jq + 2 * k + 1];
    }
#pragma unroll
    for (int k = 0; k < 4; ++k) {
      int j = jq * 4 + k;
      float4 a0 = a[2 * k], a1 = a[2 * k + 1];
      float d = xr[0] * a0.x;
      d = fmaf(xr[1], a0.y, d); d = fmaf(xr[2], a0.z, d);
      d = fmaf(xr[3], a0.w, d); d = fmaf(xr[4], a1.x, d);
      d = fmaf(xr[5], a1.y, d); d = fmaf(xr[6], a1.z, d);
      d = fmaf(xr[7], a1.w, d);
      float nj = (k == 0) ? nj4.x : (k == 1) ? nj4.y : (k == 2) ? nj4.z : nj4.w;
      float sq = fmaf(-2.0f, d, nself + nj);
      float Cv = __builtin_amdgcn_sqrtf(fmaxf(sq, 0.0f) + 1e-8f);
      C[j] = Cv;
      V[j] = __builtin_amdgcn_exp2f(-Cv * K20);
    }
  }

  float* Ew = Ebuf[pl][w];

  float P = 0.0f;
  float epsv = 10.0f;

#pragma unroll 1
  for (int it = 0; it < 9; ++it) {
    float eps = (it == 8) ? 0.05f : epsv;
    float k2 = RLNE / eps;
    float eln2 = eps * LN2;
    float c32 = eps * LN32;

    if (it == 8) {
#pragma unroll
      for (int j = 0; j < 32; ++j)
        V[j] = __builtin_amdgcn_exp2f(C[j] * NK28);
    } else if (it > 0) {
#pragma unroll
      for (int j = 0; j < 32; ++j) V[j] *= V[j];
    }

    float mOwn, mRead;
    if (it >= 7) {
      float m = P;
      m = dpp_max<0x111>(m);
      m = dpp_max<0x112>(m);
      m = dpp_max<0x114>(m);
      m = dpp_max<0x118>(m);
      m = dpp_max<0x142>(m);  // lanes 31/63 hold half maxes
      float g0 = __int_as_float(__builtin_amdgcn_readlane(__float_as_int(m), 31));
      float g1 = __int_as_float(__builtin_amdgcn_readlane(__float_as_int(m), 63));
      mOwn = own ? g1 : g0;
      mRead = (w == 0) ? (own ? g0 : g1) : mOwn;
    } else {
      mOwn = 0.0f;
      mRead = 0.0f;
    }

    Ew[l] = __builtin_amdgcn_exp2f((P - mOwn) * k2);
    __builtin_amdgcn_wave_barrier();

    float s0 = 0.f, s1 = 0.f, s2 = 0.f, s3 = 0.f;
#pragma unroll
    for (int jq = 0; jq < 8; ++jq) {
      float4 Ev = ((const float4*)(Ew + rb))[jq];
      s0 = fmaf(Ev.x, V[4 * jq + 0], s0);
      s1 = fmaf(Ev.y, V[4 * jq + 1], s1);
      s2 = fmaf(Ev.z, V[4 * jq + 2], s2);
      s3 = fmaf(Ev.w, V[4 * jq + 3], s3);
    }
    float s = fmaxf((s0 + s1) + (s2 + s3), 1e-37f);
    __builtin_amdgcn_wave_barrier();  // reads complete before next write

    P = 0.5f * (P + (c32 - mRead - eln2 * __builtin_amdgcn_logf(s)));
    epsv *= 0.5f;
  }

  // wave sums via DPP
  float d = P;
  d = dpp_add<0x111>(d);
  d = dpp_add<0x112>(d);
  d = dpp_add<0x114>(d);
  d = dpp_add<0x118>(d);
  d = dpp_add<0x142>(d);
  float s31 = __int_as_float(__builtin_amdgcn_readlane(__float_as_int(d), 31));
  float s63 = __int_as_float(__builtin_amdgcn_readlane(__float_as_int(d), 63));
  if (l == 0) red[pl][w] = s31 + s63;
  __syncthreads();
  if (t == 0) {
    float tot = 0.0f;
#pragma unroll
    for (int q = 0; q < 2; ++q) {
      int pr = blockIdx.x * 2 + q;
      float e = (red[q][0] - red[q][1]) * (1.0f / 32.0f);
      float term;
      if (pr < nP) {
        term = e * e;
      } else {
        float mm = fmaxf(1.0f - e, 0.0f);
        term = mm * mm;
      }
      tot += term;
    }
    partial[blockIdx.x] = tot;   // no atomics: per-block partial
  }
}

// single-block final reduction: out = sum(partial) / nP
__global__ __launch_bounds__(1024) void sge_reduce(
    const float* __restrict__ partial, int n, float invnP,
    float* __restrict__ out) {
  __shared__ float ws[16];
  float s = 0.0f;
  for (int i = threadIdx.x; i < n; i += 1024) s += partial[i];
#pragma unroll
  for (int o = 1; o < 64; o <<= 1) s += __shfl_xor(s, o);
  if ((threadIdx.x & 63) == 0) ws[threadIdx.x >> 6] = s;
  __syncthreads();
  if (threadIdx.x == 0) {
    float tt = 0.0f;
#pragma unroll
    for (int q = 0; q < 16; ++q) tt += ws[q];
    out[0] = tt * invnP;
  }
}

// ---------------------------------------------------------------------------
extern "C" void kernel_launch(void* const* d_in, const int* in_sizes, int n_in,
                              void* d_out, int out_size, void* d_ws, size_t ws_size,
                              hipStream_t stream) {
  const float* x  = (const float*)d_in[0];
  const int*   ei = (const int*)d_in[1];
  const int*   ep = (const int*)d_in[2];
  const int*   en = (const int*)d_in[3];
  const float* W  = (const float*)d_in[4];
  float* out = (float*)d_out;

  int N  = in_sizes[0] / 128;   // 100000 nodes
  int nE = in_sizes[1] / 2;     // 1600000 edges
  int nP = in_sizes[2] / 2;     // 30000 pos (== neg)

  size_t zBytes   = (size_t)N * 256 * sizeof(float);
  size_t aggBytes = (size_t)N * 128 * sizeof(float);
  if (ws_size < zBytes + aggBytes) return;

  char* ws = (char*)d_ws;
  float* z = (float*)ws;  // [0, zBytes): written by gemm, read by energy

  // CSR temporaries + partials AFTER the z region (no overlap with z)
  int* base2      = (int*)(ws + zBytes);
  int* cnt        = base2;                 // N
  int* offs       = cnt + N;               // N+1
  int* pos        = offs + N + 1;          // N
  int* bsum       = pos + N;               // <= 4096
  int* sorted_src = bsum + 4096;           // nE
  float* partial  = (float*)(sorted_src + nE);  // nP floats

  int nb = (N + 255) / 256;

  hipMemsetAsync(cnt, 0, (size_t)N * sizeof(int), stream);

  const int* src = ei;
  const int* dst = ei + nE;

  int eb = (nE + 255) / 256;
  sge_count<<<eb, 256, 0, stream>>>(dst, cnt, nE);
  sge_blocksum<<<nb, 256, 0, stream>>>(cnt, bsum, N);
  sge_scan_top<<<1, 64, 0, stream>>>(bsum, offs, nb, N, nE);
  sge_scan_block<<<nb, 256, 0, stream>>>(cnt, bsum, offs, pos, N);
  sge_fill<<<eb, 256, 0, stream>>>(src, dst, pos, sorted_src, nE);

  sge_gemm<<<(N + 31) / 32, 256, 0, stream>>>(x, sorted_src, offs, W, z);

  sge_energy<<<nP, 256, 0, stream>>>(z, ep, en, partial, nP);
  sge_reduce<<<1, 1024, 0, stream>>>(partial, nP, 1.0f / (float)nP, out);
}

// Round 22
// 647.079 us; speedup vs baseline: 1.0549x; 1.0213x over previous
//
#include <hip/hip_runtime.h>
#include <hip/hip_bf16.h>

// ---------------------------------------------------------------------------
// Phase 1a: CSR build by dst
// ---------------------------------------------------------------------------

__global__ __launch_bounds__(256) void sge_count(
    const int* __restrict__ dst, int* __restrict__ cnt, int nE) {
  int e = blockIdx.x * 256 + threadIdx.x;
  if (e >= nE) return;
  atomicAdd(&cnt[dst[e]], 1);
}

__global__ __launch_bounds__(256) void sge_blocksum(
    const int* __restrict__ cnt, int* __restrict__ bsum, int N) {
  int i = blockIdx.x * 256 + threadIdx.x;
  int v = (i < N) ? cnt[i] : 0;
#pragma unroll
  for (int o = 1; o < 64; o <<= 1) v += __shfl_xor(v, o);
  __shared__ int ws[4];
  int lane = threadIdx.x & 63, wid = threadIdx.x >> 6;
  if (lane == 0) ws[wid] = v;
  __syncthreads();
  if (threadIdx.x == 0)
    bsum[blockIdx.x] = ws[0] + ws[1] + ws[2] + ws[3];
}

__global__ __launch_bounds__(64) void sge_scan_top(
    int* __restrict__ bsum, int* __restrict__ offs, int nb, int N, int nE) {
  int lane = threadIdx.x;
  int carry = 0;
  for (int base = 0; base < nb; base += 64) {
    int i = base + lane;
    int v = (i < nb) ? bsum[i] : 0;
    int s = v;
#pragma unroll
    for (int o = 1; o < 64; o <<= 1) {
      int t = __shfl_up(s, o);
      if (lane >= o) s += t;
    }
    if (i < nb) bsum[i] = carry + s - v;  // exclusive
    carry += __shfl(s, 63);
  }
  if (lane == 0) offs[N] = nE;
}

__global__ __launch_bounds__(256) void sge_scan_block(
    const int* __restrict__ cnt, const int* __restrict__ bsum,
    int* __restrict__ offs, int* __restrict__ pos, int N) {
  int i = blockIdx.x * 256 + threadIdx.x;
  int v = (i < N) ? cnt[i] : 0;
  int lane = threadIdx.x & 63, wid = threadIdx.x >> 6;
  int s = v;
#pragma unroll
  for (int o = 1; o < 64; o <<= 1) {
    int t = __shfl_up(s, o);
    if (lane >= o) s += t;
  }
  __shared__ int ws[4];
  if (lane == 63) ws[wid] = s;
  __syncthreads();
  int wbase = 0;
  for (int w = 0; w < wid; ++w) wbase += ws[w];
  if (i < N) {
    int o = bsum[blockIdx.x] + wbase + s - v;
    offs[i] = o;
    pos[i] = o;
  }
}

__global__ __launch_bounds__(256) void sge_fill(
    const int* __restrict__ src, const int* __restrict__ dst,
    int* __restrict__ pos, int* __restrict__ sorted_src, int nE) {
  int e = blockIdx.x * 256 + threadIdx.x;
  if (e >= nE) return;
  int p = atomicAdd(&pos[dst[e]], 1);
  sorted_src[p] = src[e];
}

// ---------------------------------------------------------------------------
// Phase 1b (fused): gather-aggregate INTO the LDS tile, then z = xs @ W.
// Simple 1-edge gather loop (R21's 2-edge unroll regressed: reg pressure).
// CSR arrays live AFTER the z region (no overlay with z writes).
// ---------------------------------------------------------------------------
__global__ __launch_bounds__(256) void sge_gemm(
    const float* __restrict__ x, const int* __restrict__ sorted_src,
    const int* __restrict__ offs, const float* __restrict__ W,
    float* __restrict__ z) {
  __shared__ float xs[32][128];
  int n0 = blockIdx.x * 32;
  int t = threadIdx.x;

  {
    int r = t >> 3;          // node slot 0..31
    int c0 = (t & 7) << 4;   // 16-column span
    int node = n0 + r;       // N % 32 == 0: always valid
    int e0 = offs[node], e1 = offs[node + 1];
    float4 a0 = {0.f, 0.f, 0.f, 0.f}, a1 = {0.f, 0.f, 0.f, 0.f};
    float4 a2 = {0.f, 0.f, 0.f, 0.f}, a3 = {0.f, 0.f, 0.f, 0.f};
    for (int e = e0; e < e1; ++e) {
      int s = sorted_src[e];  // uniform across the 8 threads of this node
      const float4* xr = (const float4*)&x[(size_t)s * 128 + c0];
      float4 v0 = xr[0], v1 = xr[1], v2 = xr[2], v3 = xr[3];
      a0.x += v0.x; a0.y += v0.y; a0.z += v0.z; a0.w += v0.w;
      a1.x += v1.x; a1.y += v1.y; a1.z += v1.z; a1.w += v1.w;
      a2.x += v2.x; a2.y += v2.y; a2.z += v2.z; a2.w += v2.w;
      a3.x += v3.x; a3.y += v3.y; a3.z += v3.z; a3.w += v3.w;
    }
    float inv = 1.0f / fmaxf((float)(e1 - e0), 1.0f);
    float4* xw = (float4*)&xs[r][c0];
    float4 w0, w1, w2, w3;
    w0.x = a0.x * inv; w0.y = a0.y * inv; w0.z = a0.z * inv; w0.w = a0.w * inv;
    w1.x = a1.x * inv; w1.y = a1.y * inv; w1.z = a1.z * inv; w1.w = a1.w * inv;
    w2.x = a2.x * inv; w2.y = a2.y * inv; w2.z = a2.z * inv; w2.w = a2.w * inv;
    w3.x = a3.x * inv; w3.y = a3.y * inv; w3.z = a3.z * inv; w3.w = a3.w * inv;
    xw[0] = w0; xw[1] = w1; xw[2] = w2; xw[3] = w3;
  }
  __syncthreads();

  int wv = t >> 6, lane = t & 63;
  int r0 = wv * 8;
  float acc[8][4];
#pragma unroll
  for (int r = 0; r < 8; ++r)
#pragma unroll
    for (int q = 0; q < 4; ++q) acc[r][q] = 0.f;
  for (int k = 0; k < 128; k += 4) {
    float4 xv[8];
#pragma unroll
    for (int r = 0; r < 8; ++r) xv[r] = *(const float4*)&xs[r0 + r][k];
#pragma unroll
    for (int kk = 0; kk < 4; ++kk) {
      const float* Wr = W + (k + kk) * 256 + lane;
      float w0 = Wr[0], w1 = Wr[64], w2 = Wr[128], w3 = Wr[192];
#pragma unroll
      for (int r = 0; r < 8; ++r) {
        float xk = (kk == 0) ? xv[r].x
                 : (kk == 1) ? xv[r].y
                 : (kk == 2) ? xv[r].z : xv[r].w;
        acc[r][0] = fmaf(xk, w0, acc[r][0]);
        acc[r][1] = fmaf(xk, w1, acc[r][1]);
        acc[r][2] = fmaf(xk, w2, acc[r][2]);
        acc[r][3] = fmaf(xk, w3, acc[r][3]);
      }
    }
  }
#pragma unroll
  for (int r = 0; r < 8; ++r) {
    float* zr = z + (long long)(n0 + r0 + r) * 256 + lane;
#pragma unroll
    for (int q = 0; q < 4; ++q) zr[q * 64] = acc[r][q];
  }
}

// ---------------------------------------------------------------------------
// Phase 2 (v14, FROZEN — verified 4x): norm-form build via per-wave LDS norm
// exchange, global-direct column reads, C kept for the final-eps fresh-exp
// refresh, max-skip for iters 0..6, per-block partials (no atomics).
// ---------------------------------------------------------------------------
template <int CTRL>
__device__ __forceinline__ float dpp_max(float x) {
  int r = __builtin_amdgcn_update_dpp(__float_as_int(x), __float_as_int(x),
                                      CTRL, 0xF, 0xF, false);
  return fmaxf(x, __int_as_float(r));
}
template <int CTRL>
__device__ __forceinline__ float dpp_add(float x) {
  int r = __builtin_amdgcn_update_dpp(0, __float_as_int(x), CTRL, 0xF, 0xF, true);
  return x + __int_as_float(r);
}

__global__ __launch_bounds__(256, 4) void sge_energy(
    const float* __restrict__ z, const int* __restrict__ ep,
    const int* __restrict__ en, float* __restrict__ partial, int nP) {
  __shared__ __align__(16) float Ebuf[2][2][64];  // [pair][wave][64]
  __shared__ __align__(16) float Nbuf[2][2][64];  // [pair][wave][64] norms
  __shared__ float red[2][2];

  int t = threadIdx.x;
  int pl = t >> 7;        // pair-local index 0/1
  int tp = t & 127;       // thread within pair
  int w = tp >> 6;        // wave-in-pair: 0={xy,yx}, 1={xx,yy}
  int l = tp & 63;
  int row = l & 31;
  int own = l & 32;       // 0 = x-rows half, 32 = y-rows half

  int pair = blockIdx.x * 2 + pl;
  bool isPos = pair < nP;
  int idx = isPos ? pair : pair - nP;
  const int* E = isPos ? ep : en;
  int na = E[idx], nb = E[idx + nP];

  // own row straight from global
  const float* zrow = z + (size_t)(own ? nb : na) * 256 + row * 8;
  float4 r0 = ((const float4*)zrow)[0];
  float4 r1 = ((const float4*)zrow)[1];
  float xr[8];
  xr[0] = r0.x; xr[1] = r0.y; xr[2] = r0.z; xr[3] = r0.w;
  xr[4] = r1.x; xr[5] = r1.y; xr[6] = r1.z; xr[7] = r1.w;

  // own squared norm -> LDS exchange (same rb addressing as Ebuf)
  float nself = xr[0] * xr[0];
  nself = fmaf(xr[1], xr[1], nself); nself = fmaf(xr[2], xr[2], nself);
  nself = fmaf(xr[3], xr[3], nself); nself = fmaf(xr[4], xr[4], nself);
  nself = fmaf(xr[5], xr[5], nself); nself = fmaf(xr[6], xr[6], nself);
  nself = fmaf(xr[7], xr[7], nself);
  Nbuf[pl][w][l] = nself;
  __builtin_amdgcn_wave_barrier();

  bool colIsX = (w == 0) ? (own != 0) : (own == 0);
  const float4* zc = (const float4*)(z + (size_t)(colIsX ? na : nb) * 256);
  int rb = (w == 0) ? (own ^ 32) : own;
  const float* Nw = Nbuf[pl][w] + rb;

  const float RLNE = 1.44269504088896340736f;  // log2(e)
  const float LN2 = 0.69314718055994530942f;
  const float LN32 = 3.46573590279972654709f;  // ln(32)
  const float K20 = RLNE / 10.0f;
  const float NK28 = -RLNE / 0.05f;            // -k2 at final eps

  // build C (kept) and V = 2^(-C*k2_0); norm-form distance
  float C[32], V[32];
#pragma unroll
  for (int jq = 0; jq < 8; ++jq) {
    float4 nj4 = ((const float4*)Nw)[jq];
    float4 a[8];
#pragma unroll
    for (int k = 0; k < 4; ++k) {
      a[2 * k] = zc[8 * jq + 2 * k];
      a[2 * k + 1] = zc[8 * jq + 2 * k + 1];
    }
#pragma unroll
    for (int k = 0; k < 4; ++k) {
      int j = jq * 4 + k;
      float4 a0 = a[2 * k], a1 = a[2 * k + 1];
      float d = xr[0] * a0.x;
      d = fmaf(xr[1], a0.y, d); d = fmaf(xr[2], a0.z, d);
      d = fmaf(xr[3], a0.w, d); d = fmaf(xr[4], a1.x, d);
      d = fmaf(xr[5], a1.y, d); d = fmaf(xr[6], a1.z, d);
      d = fmaf(xr[7], a1.w, d);
      float nj = (k == 0) ? nj4.x : (k == 1) ? nj4.y : (k == 2) ? nj4.z : nj4.w;
      float sq = fmaf(-2.0f, d, nself + nj);
      float Cv = __builtin_amdgcn_sqrtf(fmaxf(sq, 0.0f) + 1e-8f);
      C[j] = Cv;
      V[j] = __builtin_amdgcn_exp2f(-Cv * K20);
    }
  }

  float* Ew = Ebuf[pl][w];

  float P = 0.0f;
  float epsv = 10.0f;

#pragma unroll 1
  for (int it = 0; it < 9; ++it) {
    float eps = (it == 8) ? 0.05f : epsv;
    float k2 = RLNE / eps;
    float eln2 = eps * LN2;
    float c32 = eps * LN32;

    if (it == 8) {
#pragma unroll
      for (int j = 0; j < 32; ++j)
        V[j] = __builtin_amdgcn_exp2f(C[j] * NK28);
    } else if (it > 0) {
#pragma unroll
      for (int j = 0; j < 32; ++j) V[j] *= V[j];
    }

    float mOwn, mRead;
    if (it >= 7) {
      float m = P;
      m = dpp_max<0x111>(m);
      m = dpp_max<0x112>(m);
      m = dpp_max<0x114>(m);
      m = dpp_max<0x118>(m);
      m = dpp_max<0x142>(m);  // lanes 31/63 hold half maxes
      float g0 = __int_as_float(__builtin_amdgcn_readlane(__float_as_int(m), 31));
      float g1 = __int_as_float(__builtin_amdgcn_readlane(__float_as_int(m), 63));
      mOwn = own ? g1 : g0;
      mRead = (w == 0) ? (own ? g0 : g1) : mOwn;
    } else {
      mOwn = 0.0f;
      mRead = 0.0f;
    }

    Ew[l] = __builtin_amdgcn_exp2f((P - mOwn) * k2);
    __builtin_amdgcn_wave_barrier();

    float s0 = 0.f, s1 = 0.f, s2 = 0.f, s3 = 0.f;
#pragma unroll
    for (int jq = 0; jq < 8; ++jq) {
      float4 Ev = ((const float4*)(Ew + rb))[jq];
      s0 = fmaf(Ev.x, V[4 * jq + 0], s0);
      s1 = fmaf(Ev.y, V[4 * jq + 1], s1);
      s2 = fmaf(Ev.z, V[4 * jq + 2], s2);
      s3 = fmaf(Ev.w, V[4 * jq + 3], s3);
    }
    float s = fmaxf((s0 + s1) + (s2 + s3), 1e-37f);
    __builtin_amdgcn_wave_barrier();  // reads complete before next write

    P = 0.5f * (P + (c32 - mRead - eln2 * __builtin_amdgcn_logf(s)));
    epsv *= 0.5f;
  }

  // wave sums via DPP
  float d = P;
  d = dpp_add<0x111>(d);
  d = dpp_add<0x112>(d);
  d = dpp_add<0x114>(d);
  d = dpp_add<0x118>(d);
  d = dpp_add<0x142>(d);
  float s31 = __int_as_float(__builtin_amdgcn_readlane(__float_as_int(d), 31));
  float s63 = __int_as_float(__builtin_amdgcn_readlane(__float_as_int(d), 63));
  if (l == 0) red[pl][w] = s31 + s63;
  __syncthreads();
  if (t == 0) {
    float tot = 0.0f;
#pragma unroll
    for (int q = 0; q < 2; ++q) {
      int pr = blockIdx.x * 2 + q;
      float e = (red[q][0] - red[q][1]) * (1.0f / 32.0f);
      float term;
      if (pr < nP) {
        term = e * e;
      } else {
        float mm = fmaxf(1.0f - e, 0.0f);
        term = mm * mm;
      }
      tot += term;
    }
    partial[blockIdx.x] = tot;   // no atomics: per-block partial
  }
}

// single-block final reduction: out = sum(partial) / nP
__global__ __launch_bounds__(1024) void sge_reduce(
    const float* __restrict__ partial, int n, float invnP,
    float* __restrict__ out) {
  __shared__ float ws[16];
  float s = 0.0f;
  for (int i = threadIdx.x; i < n; i += 1024) s += partial[i];
#pragma unroll
  for (int o = 1; o < 64; o <<= 1) s += __shfl_xor(s, o);
  if ((threadIdx.x & 63) == 0) ws[threadIdx.x >> 6] = s;
  __syncthreads();
  if (threadIdx.x == 0) {
    float tt = 0.0f;
#pragma unroll
    for (int q = 0; q < 16; ++q) tt += ws[q];
    out[0] = tt * invnP;
  }
}

// ---------------------------------------------------------------------------
extern "C" void kernel_launch(void* const* d_in, const int* in_sizes, int n_in,
                              void* d_out, int out_size, void* d_ws, size_t ws_size,
                              hipStream_t stream) {
  const float* x  = (const float*)d_in[0];
  const int*   ei = (const int*)d_in[1];
  const int*   ep = (const int*)d_in[2];
  const int*   en = (const int*)d_in[3];
  const float* W  = (const float*)d_in[4];
  float* out = (float*)d_out;

  int N  = in_sizes[0] / 128;   // 100000 nodes
  int nE = in_sizes[1] / 2;     // 1600000 edges
  int nP = in_sizes[2] / 2;     // 30000 pos (== neg)

  size_t zBytes   = (size_t)N * 256 * sizeof(float);
  size_t aggBytes = (size_t)N * 128 * sizeof(float);
  if (ws_size < zBytes + aggBytes) return;

  char* ws = (char*)d_ws;
  float* z = (float*)ws;  // [0, zBytes): written by gemm, read by energy

  // CSR temporaries + partials AFTER the z region (no overlap with z)
  int* base2      = (int*)(ws + zBytes);
  int* cnt        = base2;                 // N
  int* offs       = cnt + N;               // N+1
  int* pos        = offs + N + 1;          // N
  int* bsum       = pos + N;               // <= 4096
  int* sorted_src = bsum + 4096;           // nE
  float* partial  = (float*)(sorted_src + nE);  // nP floats

  int nb = (N + 255) / 256;

  hipMemsetAsync(cnt, 0, (size_t)N * sizeof(int), stream);

  const int* src = ei;
  const int* dst = ei + nE;

  int eb = (nE + 255) / 256;
  sge_count<<<eb, 256, 0, stream>>>(dst, cnt, nE);
  sge_blocksum<<<nb, 256, 0, stream>>>(cnt, bsum, N);
  sge_scan_top<<<1, 64, 0, stream>>>(bsum, offs, nb, N, nE);
  sge_scan_block<<<nb, 256, 0, stream>>>(cnt, bsum, offs, pos, N);
  sge_fill<<<eb, 256, 0, stream>>>(src, dst, pos, sorted_src, nE);

  sge_gemm<<<(N + 31) / 32, 256, 0, stream>>>(x, sorted_src, offs, W, z);

  sge_energy<<<nP, 256, 0, stream>>>(z, ep, en, partial, nP);
  sge_reduce<<<1, 1024, 0, stream>>>(partial, nP, 1.0f / (float)nP, out);
}